// Round 7
// baseline (223.449 us; speedup 1.0000x reference)
//
#include <hip/hip_runtime.h>
#include <hip/hip_bf16.h>
#include <stdint.h>

// MultiHeadAttention: B=2, S=2048, D_MODEL=1024, H=16, depth=64.
// 4-launch pipeline. ~110us/iter is fixed harness restore/poison overhead;
// kernel sum is the budget.
//
//   1) setup: dtype probe, mask scan->cpos/nb, bias convert, weight
//      transpose (64x64 tiles -> full-cacheline 128B stores), qkv
//      f32->bf16 convert.
//   2) gemm_qkv (z=3): projections -> Qh[b,h,s,d], Kc[b,h,j,d], Vc[b,h,d,j]
//      R10/R12 config (best measured, 50.3us): 128x128 tile BK=32, dbuf
//      issue-early, XOR bank swizzle, LDS-bounce epilogue. Accepted at the
//      2-phase plateau (R7/R8/R9/R11 all null-to-negative; FETCH is
//      near-ideal 40.5MB). DO NOT touch without new counter evidence.
//   3) attn: flash attention over compact keys, STATIC-max softmax,
//      32 q-rows/wave, K/V reg prefetch, setprio around MFMA (R12).
//      R13: bh-major XCD remap. Old mapping XCD=qt%8 -> every XCD streams
//      all 32 bh (8MB K/V) through its 4MB L2 = thrash; every tile read is
//      L3/HBM-latency (~400-900cy) vs ~600cy/iter compute -> 1-deep reg
//      prefetch can't cover. New bijection (xcd=flat&7, bh=xcd+(g>>4)*8,
//      qt=g&15): each XCD owns 4 bh fully = 1MB K/V, L2-resident.
//   4) gemm_out: 64x128-tile kernel (512 blocks = 2/CU), dense epilogue.

typedef __bf16 bf16;
typedef __bf16 bf16x8 __attribute__((ext_vector_type(8)));
typedef __bf16 bf16x4 __attribute__((ext_vector_type(4)));
typedef float  f32x4  __attribute__((ext_vector_type(4)));

#define D_MODEL 1024
#define S_LEN   2048
#define NH      16
#define DEPTH   64

#define LOG2E   1.4426950408889634f
#define QSCALE  (0.125f * LOG2E)     // folded into wq/bq at setup time
#define SMAX    20.0f                // static softmax max (log2 domain)
#define PADPEN  (-30000.0f)          // pad keys: exp2(~-30000) == +0 exactly

__device__ __forceinline__ void gload_lds16(const void* g, void* l) {
  __builtin_amdgcn_global_load_lds(
      (__attribute__((address_space(1))) void*)g,
      (__attribute__((address_space(3))) void*)l,
      16, 0, 0);
}

// ---------------------------------------------------------------- setup
// grid: [0,2) mask scan | [2,6) bias | [6,1030) weight transpose 64x64 |
//       [1030,7174) qkv f32->bf16 convert
__global__ __launch_bounds__(256) void setup(
    const void* __restrict__ q, const void* __restrict__ k,
    const void* __restrict__ v, const int* __restrict__ mask,
    const void* __restrict__ wq, const void* __restrict__ wk,
    const void* __restrict__ wv, const void* __restrict__ wo,
    const void* __restrict__ bq, const void* __restrict__ bk,
    const void* __restrict__ bv, const void* __restrict__ bo,
    bf16* __restrict__ wqT, bf16* __restrict__ wkT,
    bf16* __restrict__ wvT, bf16* __restrict__ woT,
    bf16* __restrict__ bqb, bf16* __restrict__ bkb,
    bf16* __restrict__ bvb, bf16* __restrict__ bob,
    bf16* __restrict__ qb, bf16* __restrict__ kb, bf16* __restrict__ vb,
    int* __restrict__ cpos, int* __restrict__ nb, int* __restrict__ flagout)
{
  const int t = threadIdx.x;
  // local dtype probe: word bits[14:7] = exponent of low bf16 half;
  // bf16 data -> ~all of 256 samples in [90,150]; f32 mantissa tail -> ~61.
  uint32_t w = ((const uint32_t*)q)[t];
  uint32_t e = (w >> 7) & 0xFF;
  int inr = (e >= 90 && e <= 150) ? 1 : 0;
  __shared__ int flg;
  int cnt = __syncthreads_count(inr);
  if (t == 0) flg = (cnt > 160) ? 1 : 0;
  __syncthreads();
  int flag = flg;

  const int bid = blockIdx.x;
  if (bid < 2) {
    // ---- mask scan for batch b = bid
    const int b = bid;
    const int lane = t & 63, wv4 = t >> 6;
    __shared__ int wsum[4];
    int vals[8], s = 0;
#pragma unroll
    for (int j = 0; j < 8; ++j) {
      vals[j] = (mask[b * S_LEN + t * 8 + j] == 0) ? 1 : 0;
      s += vals[j];
    }
    int acc = s;  // wave-inclusive scan
    for (int off = 1; off < 64; off <<= 1) {
      int u = __shfl_up(acc, off);
      if (lane >= off) acc += u;
    }
    if (lane == 63) wsum[wv4] = acc;
    __syncthreads();
    int base = 0;
    for (int w4 = 0; w4 < 4; ++w4) base += (w4 < wv4) ? wsum[w4] : 0;
    int ex = base + acc - s;
#pragma unroll
    for (int j = 0; j < 8; ++j) {
      cpos[b * S_LEN + t * 8 + j] = vals[j] ? ex : -1;
      ex += vals[j];
    }
    if (t == 255) nb[b] = base + acc;
    if (b == 0 && t == 0) *flagout = flag;
  } else if (bid < 6) {
    // ---- bias convert, job = bid-2
    const int j = bid - 2;
    const void* B; bf16* O;
    switch (j) {
      case 0:  B = bq; O = bqb; break;
      case 1:  B = bk; O = bkb; break;
      case 2:  B = bv; O = bvb; break;
      default: B = bo; O = bob; break;
    }
    const float sc = (j == 0) ? QSCALE : 1.0f;
    for (int jj = 0; jj < 4; ++jj) {
      const int i = t + jj * 256;
      const float val = flag ? (float)((const bf16*)B)[i] : ((const float*)B)[i];
      O[i] = (bf16)(val * sc);
    }
  } else if (bid < 6 + 1024) {
    // ---- weight transpose, 64x64 tiles, job = bid-6
    // T[x][y] = W[y][x]*sc. Writes are 64 cols bf16 = 128B = FULL line.
    const int job = bid - 6;
    const int wsel = job >> 8, rem = job & 255;
    const void* W; bf16* T;
    switch (wsel) {
      case 0:  W = wq; T = wqT; break;
      case 1:  W = wk; T = wkT; break;
      case 2:  W = wv; T = wvT; break;
      default: W = wo; T = woT; break;
    }
    const float sc = (wsel == 0) ? QSCALE : 1.0f;
    __shared__ float tile[64][65];
    const int tx = t & 63, ty = t >> 6;        // 64 x 4
    const int x0 = (rem & 15) * 64;            // col
    const int y0 = (rem >> 4) * 64;            // row
    for (int i = ty; i < 64; i += 4) {
      const size_t gi = (size_t)(y0 + i) * D_MODEL + x0 + tx;
      tile[i][tx] = flag ? (float)((const bf16*)W)[gi] : ((const float*)W)[gi];
    }
    __syncthreads();
    // write: row x0+j, cols y0+tx (tx contiguous). LDS read tile[tx][j]:
    // addr = tx*65+j -> bank (tx+j)%32, conflict-free.
    for (int j = ty; j < 64; j += 4)
      T[(size_t)(x0 + j) * D_MODEL + y0 + tx] = (bf16)(tile[tx][j] * sc);
  } else {
    // ---- qkv f32->bf16 convert (no-op when inputs already bf16)
    if (flag) return;
    const int job = bid - 1030;
    const int tensor = job >> 11, blk = job & 2047;
    const void* src; bf16* dst;
    switch (tensor) {
      case 0:  src = q; dst = qb; break;
      case 1:  src = k; dst = kb; break;
      default: src = v; dst = vb; break;
    }
    const size_t idx = ((size_t)blk * 256 + t) * 8;
    const float* s = (const float*)src + idx;
    f32x4 a = *(const f32x4*)(s);
    f32x4 b2 = *(const f32x4*)(s + 4);
    bf16x8 o;
    for (int i = 0; i < 4; ++i) { o[i] = (bf16)a[i]; o[4 + i] = (bf16)b2[i]; }
    *(bf16x8*)(dst + idx) = o;
  }
}

// ---------------------------------------------------------------- GEMM A@B^T
// M=4096, N=1024, K=1024. 128x128 tile, 4 waves (2x2 of 64x64), BK=32.
// Block (x,y) XCD-swizzled: assuming XCD = flat%8 round-robin, each XCD gets
// a 4(x) x 8(y) rectangle -> A row-panel fetched by 2 XCDs instead of 8.
//
// K-loop (R7/R10, best measured): double-buffered LDS (2x16KB). Per K-step:
// issue next tile's global_load_lds FIRST, then ds_read+MFMA on current
// buffer, then ONE __syncthreads. Bank swizzle f(row)=(row>>1)&3 on the
// 8-elem chunk index, applied on the GLOBAL source side (LDS dest stays
// linear) and mirrored on the fragment-read side.
//
// Epilogue (R10): wave-private LDS strip bounce (aliases dead As buffer).
struct GArgs {
  const bf16* A;     // converted A (used when flag==0)
  const void* Araw;  // original input (used as bf16 when flag==1)
  const bf16* BT;    // [1024][1024] bf16, row n = column n of W
  const bf16* bias;  // [1024] bf16
  void* out;
  const int* cpos;   // compact index per (b,s), modes 2/3 only
  int mode;          // 0: [m][n] per flag  1: Qh[b,h,s,d]
                     // 2: Vc[b,h,d,j] compact  3: Kc[b,h,j,d] compact
};

__device__ __forceinline__ void gemm_body(const GArgs& g, int flag)
{
  const bf16* A = flag ? (const bf16*)g.Araw : g.A;

  __shared__ __align__(16) bf16 As[2][128 * 32];
  __shared__ __align__(16) bf16 Bs[2][128 * 32];
  const int tid  = threadIdx.x;
  const int wave = tid >> 6, lane = tid & 63;
  const int quad = lane >> 4, l16 = lane & 15;

  // XCD swizzle (8 x-tiles, 32 y-tiles per z-slice)
  const int flat = blockIdx.y * 8 + blockIdx.x;
  const int xcd = flat & 7, pos = flat >> 3;           // pos 0..31
  const int bx = (xcd & 1) * 4 + (pos & 3);
  const int by = (xcd >> 1) * 8 + (pos >> 2);
  const int m0 = by * 128, n0 = bx * 128;

  const int wm = (wave >> 1) * 64, wn = (wave & 1) * 64;
  const int srow = lane >> 2;
  // XOR-swizzled global source chunk: lane covers LDS slot (srow, lane&3);
  // that slot must hold logical chunk (lane&3) ^ f(srow), f(r)=(r>>1)&3.
  const int scol = (((lane & 3) ^ ((lane >> 3) & 3)) * 8);

  f32x4 acc[4][4] = {};

  const bf16* Ag = A    + (size_t)(m0 + wave * 32 + srow) * D_MODEL + scol;
  const bf16* Bg = g.BT + (size_t)(n0 + wave * 32 + srow) * D_MODEL + scol;
  const int lbase = (wave * 32) * 32;   // wave-uniform LDS element base
  // swizzled fragment-read chunk: slot = quad ^ f(row), f = l16 bits 1..2
  const int rsw = (quad ^ ((l16 >> 1) & 3)) * 8;

  // prologue: stage K-tile 0 into buffer 0
  gload_lds16(Ag,                &As[0][lbase]);
  gload_lds16(Ag + 16 * D_MODEL, &As[0][lbase + 16 * 32]);
  gload_lds16(Bg,                &Bs[0][lbase]);
  gload_lds16(Bg + 16 * D_MODEL, &Bs[0][lbase + 16 * 32]);
  __syncthreads();

  int cur = 0;
  for (int kt = 0; kt < D_MODEL; kt += 32, cur ^= 1) {
    if (kt + 32 < D_MODEL) {             // issue next-tile stage (async)
      const int nxt = cur ^ 1;
      gload_lds16(Ag + kt + 32,                &As[nxt][lbase]);
      gload_lds16(Ag + kt + 32 + 16 * D_MODEL, &As[nxt][lbase + 16 * 32]);
      gload_lds16(Bg + kt + 32,                &Bs[nxt][lbase]);
      gload_lds16(Bg + kt + 32 + 16 * D_MODEL, &Bs[nxt][lbase + 16 * 32]);
    }

    bf16x8 af[4], bfv[4];
#pragma unroll
    for (int mi = 0; mi < 4; ++mi)
      af[mi] = *(const bf16x8*)(&As[cur][(wm + mi * 16 + l16) * 32 + rsw]);
#pragma unroll
    for (int ni = 0; ni < 4; ++ni)
      bfv[ni] = *(const bf16x8*)(&Bs[cur][(wn + ni * 16 + l16) * 32 + rsw]);
#pragma unroll
    for (int mi = 0; mi < 4; ++mi)
#pragma unroll
      for (int ni = 0; ni < 4; ++ni)
        acc[mi][ni] = __builtin_amdgcn_mfma_f32_16x16x32_bf16(
            af[mi], bfv[ni], acc[mi][ni], 0, 0, 0);

    __syncthreads();   // drains vmcnt(0): next tile published; buffers swap
  }
  // After the final loop-end __syncthreads, all waves are done reading
  // As/Bs -> As is dead and reusable as the epilogue bounce buffer.

  if (g.mode != 0) {
    // ---- LDS-bounce epilogue (modes 1/2/3). Wave-private strip: 16 rows
    // (s) x 64 cols (wave's n-range), stride 72 elems (bank-spread).
    bf16* strip = ((bf16*)As) + wave * (16 * 72);
    const int hh = (n0 + wn) >> 6;     // wave's 64-col range = one head
    float bvf[4];
#pragma unroll
    for (int ni = 0; ni < 4; ++ni)
      bvf[ni] = (float)g.bias[n0 + wn + ni * 16 + l16];

#pragma unroll
    for (int mi = 0; mi < 4; ++mi) {
      const int row0 = m0 + wm + mi * 16;      // global row of strip base
      const int b = row0 >> 11, s0 = row0 & 2047;

      // 1) fragments -> strip (C layout: row=quad*4+r, col=ni*16+l16)
#pragma unroll
      for (int ni = 0; ni < 4; ++ni)
#pragma unroll
        for (int r = 0; r < 4; ++r)
          strip[(quad * 4 + r) * 72 + ni * 16 + l16] =
              (bf16)(acc[mi][ni][r] + bvf[ni]);
      // same-wave DS ordering: reads below see the writes above.

      if (g.mode == 1) {              // Qh[b,h,s,d]: dense 128B rows
        bf16* ob = (bf16*)g.out +
                   ((size_t)(b * NH + hh) * S_LEN + s0) * DEPTH;
#pragma unroll
        for (int half = 0; half < 2; ++half) {
          const int rl = half * 8 + (lane >> 3);
          bf16x8 vv = *(const bf16x8*)(strip + rl * 72 + (lane & 7) * 8);
          *(bf16x8*)(ob + (size_t)rl * DEPTH + (lane & 7) * 8) = vv;
        }
      } else if (g.mode == 3) {       // Kc[b,h,j,d]: dense rows at compact j
        bf16* kb = (bf16*)g.out + (size_t)(b * NH + hh) * S_LEN * DEPTH;
#pragma unroll
        for (int half = 0; half < 2; ++half) {
          const int rl = half * 8 + (lane >> 3);
          const int cpv = g.cpos[b * S_LEN + s0 + rl];
          bf16x8 vv = *(const bf16x8*)(strip + rl * 72 + (lane & 7) * 8);
          if (cpv >= 0)
            *(bf16x8*)(kb + (size_t)cpv * DEPTH + (lane & 7) * 8) = vv;
        }
      } else {                        // mode 2: Vc[b,h,d,j]
        // lane covers strip row sl (=> compact col j) and d-chunk dq*16.
        // Store instr for fixed dd: 16 lanes write consecutive compact j
        // (32B runs, 4 lines) instead of 64 scattered lines.
        const int sl = lane & 15, dq = lane >> 4;
        const int cpv = g.cpos[b * S_LEN + s0 + sl];
        union { bf16x8 v; bf16 e[8]; } u0, u1;
        u0.v = *(const bf16x8*)(strip + sl * 72 + dq * 16);
        u1.v = *(const bf16x8*)(strip + sl * 72 + dq * 16 + 8);
        bf16* vb0 = (bf16*)g.out +
                    ((size_t)(b * NH + hh) * DEPTH + dq * 16) * S_LEN +
                    (cpv >= 0 ? cpv : 0);
        if (cpv >= 0) {
#pragma unroll
          for (int dd = 0; dd < 8; ++dd) vb0[(size_t)dd * S_LEN] = u0.e[dd];
#pragma unroll
          for (int dd = 0; dd < 8; ++dd)
            vb0[(size_t)(dd + 8) * S_LEN] = u1.e[dd];
        }
      }
    }
    return;
  }

  // ---- mode 0 epilogue: dense row writes
#pragma unroll
  for (int mi = 0; mi < 4; ++mi) {
    const int row0 = m0 + wm + mi * 16 + quad * 4;
#pragma unroll
    for (int ni = 0; ni < 4; ++ni) {
      const int col  = n0 + wn + ni * 16 + l16;
      const float bv = (float)g.bias[col];
      if (flag) {
        bf16* op = (bf16*)g.out + (size_t)row0 * D_MODEL + col;
#pragma unroll
        for (int r = 0; r < 4; ++r)
          op[(size_t)r * D_MODEL] = (bf16)(acc[mi][ni][r] + bv);
      } else {
        float* op = (float*)g.out + (size_t)row0 * D_MODEL + col;
#pragma unroll
        for (int r = 0; r < 4; ++r)
          op[(size_t)r * D_MODEL] = acc[mi][ni][r] + bv;
      }
    }
  }
}

__global__ __launch_bounds__(256) void gemm_qkv(GArgs g0, GArgs g1, GArgs g2,
                                                const int* __restrict__ flagp)
{
  const GArgs& g = (blockIdx.z == 0) ? g0 : ((blockIdx.z == 1) ? g1 : g2);
  gemm_body(g, *flagp);
}

// ---------------------------------------------------------------- gemm_out
// 64x128 tile, 4 waves (2x2 of 32x64), BK=32, grid (8,64) = 512 blocks =
// 2 blocks/CU. Mode-0 dense epilogue only. Same dbuf + XOR swizzle.
__global__ __launch_bounds__(256) void gemm_out(GArgs g,
                                                const int* __restrict__ flagp)
{
  const int flag = *flagp;
  const bf16* A = (const bf16*)g.A;    // Oh (always bf16)

  __shared__ __align__(16) bf16 As[2][64 * 32];    //  4KB x2
  __shared__ __align__(16) bf16 Bs[2][128 * 32];   //  8KB x2
  const int tid  = threadIdx.x;
  const int wave = tid >> 6, lane = tid & 63;
  const int quad = lane >> 4, l16 = lane & 15;

  // XCD swizzle (8 bx, 64 by; 4x16 rectangles per XCD)
  const int flat = blockIdx.y * 8 + blockIdx.x;
  const int xcd = flat & 7, pos = flat >> 3;           // pos 0..63
  const int bx = (xcd & 1) * 4 + (pos & 3);
  const int by = (xcd >> 1) * 16 + (pos >> 2);
  const int m0 = by * 64, n0 = bx * 128;

  const int wm = (wave >> 1) * 32, wn = (wave & 1) * 64;
  const int srow = lane >> 2;
  const int scol = (((lane & 3) ^ ((lane >> 3) & 3)) * 8);

  f32x4 acc[2][4] = {};

  const bf16* Ag = A    + (size_t)(m0 + wave * 16 + (lane >> 2)) * D_MODEL + scol;
  const bf16* Bg = g.BT + (size_t)(n0 + wave * 32 + srow) * D_MODEL + scol;
  const int lbaseA = wave * 16 * 32;
  const int lbaseB = wave * 32 * 32;
  const int rsw = (quad ^ ((l16 >> 1) & 3)) * 8;

  gload_lds16(Ag,                &As[0][lbaseA]);
  gload_lds16(Bg,                &Bs[0][lbaseB]);
  gload_lds16(Bg + 16 * D_MODEL, &Bs[0][lbaseB + 16 * 32]);
  __syncthreads();

  int cur = 0;
  for (int kt = 0; kt < D_MODEL; kt += 32, cur ^= 1) {
    if (kt + 32 < D_MODEL) {
      const int nxt = cur ^ 1;
      gload_lds16(Ag + kt + 32,                &As[nxt][lbaseA]);
      gload_lds16(Bg + kt + 32,                &Bs[nxt][lbaseB]);
      gload_lds16(Bg + kt + 32 + 16 * D_MODEL, &Bs[nxt][lbaseB + 16 * 32]);
    }

    bf16x8 af[2], bfv[4];
#pragma unroll
    for (int mi = 0; mi < 2; ++mi)
      af[mi] = *(const bf16x8*)(&As[cur][(wm + mi * 16 + l16) * 32 + rsw]);
#pragma unroll
    for (int ni = 0; ni < 4; ++ni)
      bfv[ni] = *(const bf16x8*)(&Bs[cur][(wn + ni * 16 + l16) * 32 + rsw]);
#pragma unroll
    for (int mi = 0; mi < 2; ++mi)
#pragma unroll
      for (int ni = 0; ni < 4; ++ni)
        acc[mi][ni] = __builtin_amdgcn_mfma_f32_16x16x32_bf16(
            af[mi], bfv[ni], acc[mi][ni], 0, 0, 0);

    __syncthreads();
  }

#pragma unroll
  for (int mi = 0; mi < 2; ++mi) {
    const int row0 = m0 + wm + mi * 16 + quad * 4;
#pragma unroll
    for (int ni = 0; ni < 4; ++ni) {
      const int col  = n0 + wn + ni * 16 + l16;
      const float bv = (float)g.bias[col];
      if (flag) {
        bf16* op = (bf16*)g.out + (size_t)row0 * D_MODEL + col;
#pragma unroll
        for (int r = 0; r < 4; ++r)
          op[(size_t)r * D_MODEL] = (bf16)(acc[mi][ni][r] + bv);
      } else {
        float* op = (float*)g.out + (size_t)row0 * D_MODEL + col;
#pragma unroll
        for (int r = 0; r < 4; ++r)
          op[(size_t)r * D_MODEL] = acc[mi][ni][r] + bv;
      }
    }
  }
}

// ---------------------------------------------------------------- attention
// grid (16 q-tiles, 32 bh) remapped R13: flat = y*16+x, xcd = flat&7,
// g = flat>>3, bh = xcd + (g>>4)*8, qt = g&15. Bijective; XCD k owns
// bh in {k,k+8,k+16,k+24} x all 16 q-tiles -> per-XCD concurrent K/V
// working set = 4 x 256KB = 1MB (L2-resident; old mapping XCD=qt%8
// streamed all 32 bh = 8MB through 4MB L2 = thrash).
// 256 thr = 4 waves; wave w owns q-rows [q0+w*32, +32) as two 16-row
// sub-tiles. Compact keys, 64-key blocks. Static-max softmax; pad keys
// killed by -30000 penalty. K/V reg prefetch one block ahead; setprio
// around MFMA clusters (R12).
__global__ __launch_bounds__(256) void attn(
    const bf16* __restrict__ Qh, const bf16* __restrict__ Kc,
    const bf16* __restrict__ Vc, const int* __restrict__ nbp,
    bf16* __restrict__ Oh)
{
  const int flat = blockIdx.y * 16 + blockIdx.x;
  const int xcd = flat & 7, grp = flat >> 3;     // grp 0..63
  const int bh = xcd + (grp >> 4) * 8;           // 4 bh per XCD
  const int b  = bh >> 4;
  const int h  = bh & 15;
  const int q0 = (grp & 15) * 128;
  const int tid = threadIdx.x, wave = tid >> 6, lane = tid & 63;
  const int quad = lane >> 4, l16 = lane & 15;

  __shared__ __align__(16) bf16 Ks[64][72];
  __shared__ __align__(16) bf16 Vts[64][72];    // [d][j']
  __shared__ __align__(16) bf16 Ps[4][32][72];  // per-wave P tile

  const int nbv = nbp[b];
  const int nb_pad = (nbv + 63) & ~63;

  // Q fragments straight from global (Q is pre-scaled by QSCALE)
  const bf16* Qg = Qh + ((size_t)bh * S_LEN + q0 + wave * 32) * DEPTH;
  bf16x8 aq00 = *(const bf16x8*)(Qg + (size_t)l16 * DEPTH + quad * 8);
  bf16x8 aq01 = *(const bf16x8*)(Qg + (size_t)l16 * DEPTH + 32 + quad * 8);
  bf16x8 aq10 = *(const bf16x8*)(Qg + (size_t)(16 + l16) * DEPTH + quad * 8);
  bf16x8 aq11 = *(const bf16x8*)(Qg + (size_t)(16 + l16) * DEPTH + 32 + quad * 8);

  bf16x8 ones;
#pragma unroll
  for (int j = 0; j < 8; ++j) ones[j] = (bf16)1.0f;

  f32x4 o_acc[2][4] = {};
  f32x4 l_acc[2] = {};

  const bf16* Kg = Kc + (size_t)bh * S_LEN * DEPTH;
  const bf16* Vg = Vc + (size_t)bh * DEPTH * S_LEN;

  // staging coords: thread covers rows sr0 and sr1 (=sr0+32), 8 cols each
  const int sr0 = tid >> 3, sc0 = (tid & 7) * 8;
  const int sr1 = sr0 + 32;

  bf16x8 kr0, kr1, vr0, vr1;
  {
    kr0 = *(const bf16x8*)(Kg + (size_t)sr0 * DEPTH + sc0);
    kr1 = *(const bf16x8*)(Kg + (size_t)sr1 * DEPTH + sc0);
    vr0 = *(const bf16x8*)(Vg + (size_t)sr0 * S_LEN + sc0);
    vr1 = *(const bf16x8*)(Vg + (size_t)sr1 * S_LEN + sc0);
  }

  for (int kb = 0; kb < nb_pad; kb += 64) {
    __syncthreads();                       // previous tile fully consumed
    *(bf16x8*)(&Ks[sr0][sc0])  = kr0;
    *(bf16x8*)(&Ks[sr1][sc0])  = kr1;
    *(bf16x8*)(&Vts[sr0][sc0]) = vr0;
    *(bf16x8*)(&Vts[sr1][sc0]) = vr1;
    __syncthreads();                       // tile published
    if (kb + 64 < nb_pad) {                // prefetch next (overlaps compute)
      kr0 = *(const bf16x8*)(Kg + (size_t)(kb + 64 + sr0) * DEPTH + sc0);
      kr1 = *(const bf16x8*)(Kg + (size_t)(kb + 64 + sr1) * DEPTH + sc0);
      vr0 = *(const bf16x8*)(Vg + (size_t)sr0 * S_LEN + kb + 64 + sc0);
      vr1 = *(const bf16x8*)(Vg + (size_t)sr1 * S_LEN + kb + 64 + sc0);
    }

    // S = Q K^T : 32 q-rows x 64 keys; each bk pair feeds both q sub-tiles
    f32x4 sacc[2][4] = {};
    __builtin_amdgcn_s_setprio(1);
#pragma unroll
    for (int jn = 0; jn < 4; ++jn) {
      bf16x8 bk0 = *(const bf16x8*)(&Ks[jn * 16 + l16][quad * 8]);
      bf16x8 bk1 = *(const bf16x8*)(&Ks[jn * 16 + l16][32 + quad * 8]);
      sacc[0][jn] = __builtin_amdgcn_mfma_f32_16x16x32_bf16(aq00, bk0, sacc[0][jn], 0, 0, 0);
      sacc[0][jn] = __builtin_amdgcn_mfma_f32_16x16x32_bf16(aq01, bk1, sacc[0][jn], 0, 0, 0);
      sacc[1][jn] = __builtin_amdgcn_mfma_f32_16x16x32_bf16(aq10, bk0, sacc[1][jn], 0, 0, 0);
      sacc[1][jn] = __builtin_amdgcn_mfma_f32_16x16x32_bf16(aq11, bk1, sacc[1][jn], 0, 0, 0);
    }
    __builtin_amdgcn_s_setprio(0);

    // p = exp2(s - SMAX), pad keys -> exactly 0
#pragma unroll
    for (int jn = 0; jn < 4; ++jn) {
      const int key = kb + jn * 16 + l16;
      const float pen = (key < nbv) ? (-SMAX) : PADPEN;
#pragma unroll
      for (int qs = 0; qs < 2; ++qs)
#pragma unroll
        for (int r = 0; r < 4; ++r)
          Ps[wave][qs * 16 + quad * 4 + r][jn * 16 + l16] =
              (bf16)__builtin_amdgcn_exp2f(sacc[qs][jn][r] + pen);
    }

    // O += P @ V ; l += P @ 1  (Ps same-wave write->read: DS in-order)
    bf16x8 ap00 = *(const bf16x8*)(&Ps[wave][l16][quad * 8]);
    bf16x8 ap01 = *(const bf16x8*)(&Ps[wave][l16][32 + quad * 8]);
    bf16x8 ap10 = *(const bf16x8*)(&Ps[wave][16 + l16][quad * 8]);
    bf16x8 ap11 = *(const bf16x8*)(&Ps[wave][16 + l16][32 + quad * 8]);
    __builtin_amdgcn_s_setprio(1);
#pragma unroll
    for (int jd = 0; jd < 4; ++jd) {
      bf16x8 bv0 = *(const bf16x8*)(&Vts[jd * 16 + l16][quad * 8]);
      bf16x8 bv1 = *(const bf16x8*)(&Vts[jd * 16 + l16][32 + quad * 8]);
      o_acc[0][jd] = __builtin_amdgcn_mfma_f32_16x16x32_bf16(ap00, bv0, o_acc[0][jd], 0, 0, 0);
      o_acc[0][jd] = __builtin_amdgcn_mfma_f32_16x16x32_bf16(ap01, bv1, o_acc[0][jd], 0, 0, 0);
      o_acc[1][jd] = __builtin_amdgcn_mfma_f32_16x16x32_bf16(ap10, bv0, o_acc[1][jd], 0, 0, 0);
      o_acc[1][jd] = __builtin_amdgcn_mfma_f32_16x16x32_bf16(ap11, bv1, o_acc[1][jd], 0, 0, 0);
    }
    l_acc[0] = __builtin_amdgcn_mfma_f32_16x16x32_bf16(ap00, ones, l_acc[0], 0, 0, 0);
    l_acc[0] = __builtin_amdgcn_mfma_f32_16x16x32_bf16(ap01, ones, l_acc[0], 0, 0, 0);
    l_acc[1] = __builtin_amdgcn_mfma_f32_16x16x32_bf16(ap10, ones, l_acc[1], 0, 0, 0);
    l_acc[1] = __builtin_amdgcn_mfma_f32_16x16x32_bf16(ap11, ones, l_acc[1], 0, 0, 0);
    __builtin_amdgcn_s_setprio(0);
  }

#pragma unroll
  for (int qs = 0; qs < 2; ++qs) {
#pragma unroll
    for (int r = 0; r < 4; ++r) {
      const int s = q0 + wave * 32 + qs * 16 + quad * 4 + r;
      const float inv = 1.f / l_acc[qs][r];
#pragma unroll
      for (int jd = 0; jd < 4; ++jd) {
        const int d = jd * 16 + l16;
        Oh[(size_t)(b * S_LEN + s) * D_MODEL + h * DEPTH + d] =
            (bf16)(o_acc[qs][jd][r] * inv);
      }
    }
  }
}

// ---------------------------------------------------------------- launch
extern "C" void kernel_launch(void* const* d_in, const int* in_sizes, int n_in,
                              void* d_out, int out_size, void* d_ws, size_t ws_size,
                              hipStream_t stream)
{
  const void* q    = d_in[0];
  const void* k    = d_in[1];
  const void* v    = d_in[2];
  const int*  mask = (const int*)d_in[3];
  const void* wq   = d_in[4];
  const void* bq   = d_in[5];
  const void* wk   = d_in[6];
  const void* bk   = d_in[7];
  const void* wv   = d_in[8];
  const void* bv   = d_in[9];
  const void* wo   = d_in[10];
  const void* bo   = d_in[11];

  char* ws = (char*)d_ws;
  const size_t MB = 1u << 20;
  bf16* Qh  = (bf16*)(ws + 0 * MB);    // [b,h,s,d]   8 MB (pre-scaled)
  bf16* Kc  = (bf16*)(ws + 8 * MB);    // [b,h,j,d]   8 MB compact
  bf16* Vc  = (bf16*)(ws + 16 * MB);   // [b,h,d,j]   8 MB compact
  bf16* Oh  = (bf16*)(ws + 24 * MB);   // [b,s,(h d)] 8 MB
  bf16* wqT = (bf16*)(ws + 32 * MB);
  bf16* wkT = (bf16*)(ws + 34 * MB);
  bf16* wvT = (bf16*)(ws + 36 * MB);
  bf16* woT = (bf16*)(ws + 38 * MB);
  bf16* bqb = (bf16*)(ws + 40 * MB);
  bf16* bkb = (bf16*)(ws + 40 * MB + 4096);
  bf16* bvb = (bf16*)(ws + 40 * MB + 8192);
  bf16* bob = (bf16*)(ws + 40 * MB + 12288);
  int*  flag = (int*)(ws + 40 * MB + 32768);
  int*  cpos = (int*)(ws + 40 * MB + 65536);           // 16 KB
  int*  nb   = (int*)(ws + 40 * MB + 65536 + 16384);   // 8 B
  bf16* qb  = (bf16*)(ws + 41 * MB);   // f32-conversion buffers (flag==0 only)
  bf16* kb_ = (bf16*)(ws + 49 * MB);
  bf16* vb_ = (bf16*)(ws + 57 * MB);

  setup<<<7174, 256, 0, stream>>>(
      q, k, v, mask, wq, wk, wv, wo, bq, bk, bv, bo,
      wqT, wkT, wvT, woT, bqb, bkb, bvb, bob,
      qb, kb_, vb_, cpos, nb, flag);

  GArgs gq{qb,  q,  wqT, bqb, Qh, nullptr, 1};
  GArgs gk{kb_, k,  wkT, bkb, Kc, cpos,    3};
  GArgs gv{vb_, v,  wvT, bvb, Vc, cpos,    2};
  gemm_qkv<<<dim3(8, 32, 3), 256, 0, stream>>>(gq, gk, gv, flag);

  attn<<<dim3(16, 32), 256, 0, stream>>>(Qh, Kc, Vc, nb, Oh);

  GArgs go{Oh, Oh, woT, bob, d_out, nullptr, 0};
  gemm_out<<<dim3(8, 64), 256, 0, stream>>>(go, flag);
}

// Round 8
// 222.757 us; speedup vs baseline: 1.0031x; 1.0031x over previous
//
#include <hip/hip_runtime.h>
#include <hip/hip_bf16.h>
#include <stdint.h>

// MultiHeadAttention: B=2, S=2048, D_MODEL=1024, H=16, depth=64.
// 4-launch pipeline. ~110us/iter is fixed harness restore/poison overhead;
// kernel sum is the budget.
//
//   1) setup: dtype probe, mask scan->cpos/nb, bias convert, weight
//      transpose (64x64 tiles, full-line stores), qkv f32->bf16 convert.
//   2) gemm_qkv (z=3): projections -> Qh[b,h,s,d], Kc[b,h,j,d], Vc[b,h,d,j]
//      K-loop: R10 config (best): 128x128 BK=32, dbuf issue-early, XOR bank
//      swizzle. R14: mode-2 (Vc) epilogue rebuilt as BLOCK-level transposed
//      bounce. Old strip epilogue stored 16-j 32B runs -> each 128B Vc line
//      assembled by 4 blocks = ~4 partial writebacks + RMW fetch (measured:
//      WRITE 48.9MB vs 24 ideal, FETCH +10MB). New: stage the 128x128 tile
//      in dead As(head0)/Bs(head1) as [64 d][128 s] (XOR-s bank swizzle),
//      then store with 64 lanes = 64 consecutive s per instruction: active
//      lanes hit a dense compact-j run (cpos is a prefix sum -> consecutive
//      unmasked s have consecutive j) = one full-line writeback per line.
//   3) attn: flash attention over compact keys, STATIC-max softmax,
//      32 q-rows/wave, K/V reg prefetch, setprio (R12), bh-major XCD remap
//      (R13, null measured but mechanism sound, zero cost).
//   4) gemm_out: 64x128-tile kernel (512 blocks = 2/CU), dense epilogue.

typedef __bf16 bf16;
typedef __bf16 bf16x8 __attribute__((ext_vector_type(8)));
typedef __bf16 bf16x4 __attribute__((ext_vector_type(4)));
typedef float  f32x4  __attribute__((ext_vector_type(4)));

#define D_MODEL 1024
#define S_LEN   2048
#define NH      16
#define DEPTH   64

#define LOG2E   1.4426950408889634f
#define QSCALE  (0.125f * LOG2E)     // folded into wq/bq at setup time
#define SMAX    20.0f                // static softmax max (log2 domain)
#define PADPEN  (-30000.0f)          // pad keys: exp2(~-30000) == +0 exactly

__device__ __forceinline__ void gload_lds16(const void* g, void* l) {
  __builtin_amdgcn_global_load_lds(
      (__attribute__((address_space(1))) void*)g,
      (__attribute__((address_space(3))) void*)l,
      16, 0, 0);
}

// ---------------------------------------------------------------- setup
// grid: [0,2) mask scan | [2,6) bias | [6,1030) weight transpose 64x64 |
//       [1030,7174) qkv f32->bf16 convert
__global__ __launch_bounds__(256) void setup(
    const void* __restrict__ q, const void* __restrict__ k,
    const void* __restrict__ v, const int* __restrict__ mask,
    const void* __restrict__ wq, const void* __restrict__ wk,
    const void* __restrict__ wv, const void* __restrict__ wo,
    const void* __restrict__ bq, const void* __restrict__ bk,
    const void* __restrict__ bv, const void* __restrict__ bo,
    bf16* __restrict__ wqT, bf16* __restrict__ wkT,
    bf16* __restrict__ wvT, bf16* __restrict__ woT,
    bf16* __restrict__ bqb, bf16* __restrict__ bkb,
    bf16* __restrict__ bvb, bf16* __restrict__ bob,
    bf16* __restrict__ qb, bf16* __restrict__ kb, bf16* __restrict__ vb,
    int* __restrict__ cpos, int* __restrict__ nb, int* __restrict__ flagout)
{
  const int t = threadIdx.x;
  // local dtype probe: word bits[14:7] = exponent of low bf16 half;
  // bf16 data -> ~all of 256 samples in [90,150]; f32 mantissa tail -> ~61.
  uint32_t w = ((const uint32_t*)q)[t];
  uint32_t e = (w >> 7) & 0xFF;
  int inr = (e >= 90 && e <= 150) ? 1 : 0;
  __shared__ int flg;
  int cnt = __syncthreads_count(inr);
  if (t == 0) flg = (cnt > 160) ? 1 : 0;
  __syncthreads();
  int flag = flg;

  const int bid = blockIdx.x;
  if (bid < 2) {
    // ---- mask scan for batch b = bid
    const int b = bid;
    const int lane = t & 63, wv4 = t >> 6;
    __shared__ int wsum[4];
    int vals[8], s = 0;
#pragma unroll
    for (int j = 0; j < 8; ++j) {
      vals[j] = (mask[b * S_LEN + t * 8 + j] == 0) ? 1 : 0;
      s += vals[j];
    }
    int acc = s;  // wave-inclusive scan
    for (int off = 1; off < 64; off <<= 1) {
      int u = __shfl_up(acc, off);
      if (lane >= off) acc += u;
    }
    if (lane == 63) wsum[wv4] = acc;
    __syncthreads();
    int base = 0;
    for (int w4 = 0; w4 < 4; ++w4) base += (w4 < wv4) ? wsum[w4] : 0;
    int ex = base + acc - s;
#pragma unroll
    for (int j = 0; j < 8; ++j) {
      cpos[b * S_LEN + t * 8 + j] = vals[j] ? ex : -1;
      ex += vals[j];
    }
    if (t == 255) nb[b] = base + acc;
    if (b == 0 && t == 0) *flagout = flag;
  } else if (bid < 6) {
    // ---- bias convert, job = bid-2
    const int j = bid - 2;
    const void* B; bf16* O;
    switch (j) {
      case 0:  B = bq; O = bqb; break;
      case 1:  B = bk; O = bkb; break;
      case 2:  B = bv; O = bvb; break;
      default: B = bo; O = bob; break;
    }
    const float sc = (j == 0) ? QSCALE : 1.0f;
    for (int jj = 0; jj < 4; ++jj) {
      const int i = t + jj * 256;
      const float val = flag ? (float)((const bf16*)B)[i] : ((const float*)B)[i];
      O[i] = (bf16)(val * sc);
    }
  } else if (bid < 6 + 1024) {
    // ---- weight transpose, 64x64 tiles, job = bid-6
    // T[x][y] = W[y][x]*sc. Writes are 64 cols bf16 = 128B = FULL line.
    const int job = bid - 6;
    const int wsel = job >> 8, rem = job & 255;
    const void* W; bf16* T;
    switch (wsel) {
      case 0:  W = wq; T = wqT; break;
      case 1:  W = wk; T = wkT; break;
      case 2:  W = wv; T = wvT; break;
      default: W = wo; T = woT; break;
    }
    const float sc = (wsel == 0) ? QSCALE : 1.0f;
    __shared__ float tile[64][65];
    const int tx = t & 63, ty = t >> 6;        // 64 x 4
    const int x0 = (rem & 15) * 64;            // col
    const int y0 = (rem >> 4) * 64;            // row
    for (int i = ty; i < 64; i += 4) {
      const size_t gi = (size_t)(y0 + i) * D_MODEL + x0 + tx;
      tile[i][tx] = flag ? (float)((const bf16*)W)[gi] : ((const float*)W)[gi];
    }
    __syncthreads();
    // write: row x0+j, cols y0+tx (tx contiguous). LDS read tile[tx][j]:
    // addr = tx*65+j -> bank (tx+j)%32, conflict-free.
    for (int j = ty; j < 64; j += 4)
      T[(size_t)(x0 + j) * D_MODEL + y0 + tx] = (bf16)(tile[tx][j] * sc);
  } else {
    // ---- qkv f32->bf16 convert (no-op when inputs already bf16)
    if (flag) return;
    const int job = bid - 1030;
    const int tensor = job >> 11, blk = job & 2047;
    const void* src; bf16* dst;
    switch (tensor) {
      case 0:  src = q; dst = qb; break;
      case 1:  src = k; dst = kb; break;
      default: src = v; dst = vb; break;
    }
    const size_t idx = ((size_t)blk * 256 + t) * 8;
    const float* s = (const float*)src + idx;
    f32x4 a = *(const f32x4*)(s);
    f32x4 b2 = *(const f32x4*)(s + 4);
    bf16x8 o;
    for (int i = 0; i < 4; ++i) { o[i] = (bf16)a[i]; o[4 + i] = (bf16)b2[i]; }
    *(bf16x8*)(dst + idx) = o;
  }
}

// ---------------------------------------------------------------- GEMM A@B^T
// M=4096, N=1024, K=1024. 128x128 tile, 4 waves (2x2 of 64x64), BK=32.
// Block (x,y) XCD-swizzled: assuming XCD = flat%8 round-robin, each XCD gets
// a 4(x) x 8(y) rectangle -> A row-panel fetched by 2 XCDs instead of 8.
//
// K-loop (R7/R10, best measured): double-buffered LDS (2x16KB). Per K-step:
// issue next tile's global_load_lds FIRST, then ds_read+MFMA on current
// buffer, then ONE __syncthreads. Bank swizzle f(row)=(row>>1)&3 on the
// 8-elem chunk index, applied on the GLOBAL source side (LDS dest stays
// linear) and mirrored on the fragment-read side.
//
// Epilogues: mode 1/3 = R10 wave strip bounce; mode 2 = R14 block-level
// transposed bounce (line-dense Vc stores); mode 0 = dense rows direct.
struct GArgs {
  const bf16* A;     // converted A (used when flag==0)
  const void* Araw;  // original input (used as bf16 when flag==1)
  const bf16* BT;    // [1024][1024] bf16, row n = column n of W
  const bf16* bias;  // [1024] bf16
  void* out;
  const int* cpos;   // compact index per (b,s), modes 2/3 only
  int mode;          // 0: [m][n] per flag  1: Qh[b,h,s,d]
                     // 2: Vc[b,h,d,j] compact  3: Kc[b,h,j,d] compact
};

__device__ __forceinline__ void gemm_body(const GArgs& g, int flag)
{
  const bf16* A = flag ? (const bf16*)g.Araw : g.A;

  __shared__ __align__(16) bf16 As[2][128 * 32];
  __shared__ __align__(16) bf16 Bs[2][128 * 32];
  const int tid  = threadIdx.x;
  const int wave = tid >> 6, lane = tid & 63;
  const int quad = lane >> 4, l16 = lane & 15;

  // XCD swizzle (8 x-tiles, 32 y-tiles per z-slice)
  const int flat = blockIdx.y * 8 + blockIdx.x;
  const int xcd = flat & 7, pos = flat >> 3;           // pos 0..31
  const int bx = (xcd & 1) * 4 + (pos & 3);
  const int by = (xcd >> 1) * 8 + (pos >> 2);
  const int m0 = by * 128, n0 = bx * 128;

  const int wm = (wave >> 1) * 64, wn = (wave & 1) * 64;
  const int srow = lane >> 2;
  // XOR-swizzled global source chunk: lane covers LDS slot (srow, lane&3);
  // that slot must hold logical chunk (lane&3) ^ f(srow), f(r)=(r>>1)&3.
  const int scol = (((lane & 3) ^ ((lane >> 3) & 3)) * 8);

  f32x4 acc[4][4] = {};

  const bf16* Ag = A    + (size_t)(m0 + wave * 32 + srow) * D_MODEL + scol;
  const bf16* Bg = g.BT + (size_t)(n0 + wave * 32 + srow) * D_MODEL + scol;
  const int lbase = (wave * 32) * 32;   // wave-uniform LDS element base
  // swizzled fragment-read chunk: slot = quad ^ f(row), f = l16 bits 1..2
  const int rsw = (quad ^ ((l16 >> 1) & 3)) * 8;

  // prologue: stage K-tile 0 into buffer 0
  gload_lds16(Ag,                &As[0][lbase]);
  gload_lds16(Ag + 16 * D_MODEL, &As[0][lbase + 16 * 32]);
  gload_lds16(Bg,                &Bs[0][lbase]);
  gload_lds16(Bg + 16 * D_MODEL, &Bs[0][lbase + 16 * 32]);
  __syncthreads();

  int cur = 0;
  for (int kt = 0; kt < D_MODEL; kt += 32, cur ^= 1) {
    if (kt + 32 < D_MODEL) {             // issue next-tile stage (async)
      const int nxt = cur ^ 1;
      gload_lds16(Ag + kt + 32,                &As[nxt][lbase]);
      gload_lds16(Ag + kt + 32 + 16 * D_MODEL, &As[nxt][lbase + 16 * 32]);
      gload_lds16(Bg + kt + 32,                &Bs[nxt][lbase]);
      gload_lds16(Bg + kt + 32 + 16 * D_MODEL, &Bs[nxt][lbase + 16 * 32]);
    }

    bf16x8 af[4], bfv[4];
#pragma unroll
    for (int mi = 0; mi < 4; ++mi)
      af[mi] = *(const bf16x8*)(&As[cur][(wm + mi * 16 + l16) * 32 + rsw]);
#pragma unroll
    for (int ni = 0; ni < 4; ++ni)
      bfv[ni] = *(const bf16x8*)(&Bs[cur][(wn + ni * 16 + l16) * 32 + rsw]);
#pragma unroll
    for (int mi = 0; mi < 4; ++mi)
#pragma unroll
      for (int ni = 0; ni < 4; ++ni)
        acc[mi][ni] = __builtin_amdgcn_mfma_f32_16x16x32_bf16(
            af[mi], bfv[ni], acc[mi][ni], 0, 0, 0);

    __syncthreads();   // drains vmcnt(0): next tile published; buffers swap
  }
  // After the final loop-end __syncthreads, all waves are done reading
  // As/Bs -> both are dead and reusable as epilogue bounce buffers.

  if (g.mode == 2) {
    // ---- R14 block transposed bounce. Tile t[64 d][128 s] per head:
    // head0 (wn=0 waves) in As, head1 (wn=64) in Bs. s-index XOR-swizzled
    // by ((d&7)<<3) for bank spread; low 3 bits of s untouched -> 4
    // consecutive-s values stay contiguous (b64 packed write, 8B-aligned).
    bf16* tw = (wn == 0) ? (bf16*)As : (bf16*)Bs;
#pragma unroll
    for (int ni = 0; ni < 4; ++ni) {
      const int d = ni * 16 + l16;                 // 0..63 within head
      const int sw = (d & 7) << 3;
      const float bv = (float)g.bias[n0 + wn + ni * 16 + l16];
#pragma unroll
      for (int mi = 0; mi < 4; ++mi) {
        const int sA = wm + mi * 16 + quad * 4;    // multiple of 4
        bf16x4 p;
        p[0] = (bf16)(acc[mi][ni][0] + bv);
        p[1] = (bf16)(acc[mi][ni][1] + bv);
        p[2] = (bf16)(acc[mi][ni][2] + bv);
        p[3] = (bf16)(acc[mi][ni][3] + bv);
        *(bf16x4*)(tw + d * 128 + (sA ^ sw)) = p;
      }
    }
    __syncthreads();
    // store pass: wave w covers head (w&1), d in [(w>>1)*32, +32).
    // Each instruction: 64 lanes = 64 consecutive s for fixed d -> active
    // lanes write consecutive compact j (dense line coverage).
    const int bb = m0 >> 11, s0g = m0 & 2047;
    const int hsel = wave & 1, dbase = (wave >> 1) * 32;
    const int hh = (n0 >> 6) + hsel;
    const bf16* tr = hsel ? (const bf16*)Bs : (const bf16*)As;
    const int cp0 = g.cpos[bb * S_LEN + s0g + lane];
    const int cp1 = g.cpos[bb * S_LEN + s0g + 64 + lane];
#pragma unroll 4
    for (int dd = 0; dd < 32; ++dd) {
      const int d = dbase + dd;
      const int sw = (d & 7) << 3;
      bf16* vbase = (bf16*)g.out +
                    ((size_t)(bb * NH + hh) * DEPTH + d) * S_LEN;
      const bf16 v0 = tr[d * 128 + (lane ^ sw)];
      const bf16 v1 = tr[d * 128 + ((64 + lane) ^ sw)];
      if (cp0 >= 0) vbase[cp0] = v0;
      if (cp1 >= 0) vbase[cp1] = v1;
    }
    return;
  }

  if (g.mode != 0) {
    // ---- strip bounce epilogue (modes 1/3). Wave-private strip: 16 rows
    // (s) x 64 cols (wave's n-range), stride 72 elems (bank-spread).
    bf16* strip = ((bf16*)As) + wave * (16 * 72);
    const int hh = (n0 + wn) >> 6;     // wave's 64-col range = one head
    float bvf[4];
#pragma unroll
    for (int ni = 0; ni < 4; ++ni)
      bvf[ni] = (float)g.bias[n0 + wn + ni * 16 + l16];

#pragma unroll
    for (int mi = 0; mi < 4; ++mi) {
      const int row0 = m0 + wm + mi * 16;      // global row of strip base
      const int b = row0 >> 11, s0 = row0 & 2047;

      // 1) fragments -> strip (C layout: row=quad*4+r, col=ni*16+l16)
#pragma unroll
      for (int ni = 0; ni < 4; ++ni)
#pragma unroll
        for (int r = 0; r < 4; ++r)
          strip[(quad * 4 + r) * 72 + ni * 16 + l16] =
              (bf16)(acc[mi][ni][r] + bvf[ni]);
      // same-wave DS ordering: reads below see the writes above.

      if (g.mode == 1) {              // Qh[b,h,s,d]: dense 128B rows
        bf16* ob = (bf16*)g.out +
                   ((size_t)(b * NH + hh) * S_LEN + s0) * DEPTH;
#pragma unroll
        for (int half = 0; half < 2; ++half) {
          const int rl = half * 8 + (lane >> 3);
          bf16x8 vv = *(const bf16x8*)(strip + rl * 72 + (lane & 7) * 8);
          *(bf16x8*)(ob + (size_t)rl * DEPTH + (lane & 7) * 8) = vv;
        }
      } else {                        // mode 3: Kc[b,h,j,d]: dense rows
        bf16* kb = (bf16*)g.out + (size_t)(b * NH + hh) * S_LEN * DEPTH;
#pragma unroll
        for (int half = 0; half < 2; ++half) {
          const int rl = half * 8 + (lane >> 3);
          const int cpv = g.cpos[b * S_LEN + s0 + rl];
          bf16x8 vv = *(const bf16x8*)(strip + rl * 72 + (lane & 7) * 8);
          if (cpv >= 0)
            *(bf16x8*)(kb + (size_t)cpv * DEPTH + (lane & 7) * 8) = vv;
        }
      }
    }
    return;
  }

  // ---- mode 0 epilogue: dense row writes
#pragma unroll
  for (int mi = 0; mi < 4; ++mi) {
    const int row0 = m0 + wm + mi * 16 + quad * 4;
#pragma unroll
    for (int ni = 0; ni < 4; ++ni) {
      const int col  = n0 + wn + ni * 16 + l16;
      const float bv = (float)g.bias[col];
      if (flag) {
        bf16* op = (bf16*)g.out + (size_t)row0 * D_MODEL + col;
#pragma unroll
        for (int r = 0; r < 4; ++r)
          op[(size_t)r * D_MODEL] = (bf16)(acc[mi][ni][r] + bv);
      } else {
        float* op = (float*)g.out + (size_t)row0 * D_MODEL + col;
#pragma unroll
        for (int r = 0; r < 4; ++r)
          op[(size_t)r * D_MODEL] = acc[mi][ni][r] + bv;
      }
    }
  }
}

__global__ __launch_bounds__(256) void gemm_qkv(GArgs g0, GArgs g1, GArgs g2,
                                                const int* __restrict__ flagp)
{
  const GArgs& g = (blockIdx.z == 0) ? g0 : ((blockIdx.z == 1) ? g1 : g2);
  gemm_body(g, *flagp);
}

// ---------------------------------------------------------------- gemm_out
// 64x128 tile, 4 waves (2x2 of 32x64), BK=32, grid (8,64) = 512 blocks =
// 2 blocks/CU. Mode-0 dense epilogue only. Same dbuf + XOR swizzle.
__global__ __launch_bounds__(256) void gemm_out(GArgs g,
                                                const int* __restrict__ flagp)
{
  const int flag = *flagp;
  const bf16* A = (const bf16*)g.A;    // Oh (always bf16)

  __shared__ __align__(16) bf16 As[2][64 * 32];    //  4KB x2
  __shared__ __align__(16) bf16 Bs[2][128 * 32];   //  8KB x2
  const int tid  = threadIdx.x;
  const int wave = tid >> 6, lane = tid & 63;
  const int quad = lane >> 4, l16 = lane & 15;

  // XCD swizzle (8 bx, 64 by; 4x16 rectangles per XCD)
  const int flat = blockIdx.y * 8 + blockIdx.x;
  const int xcd = flat & 7, pos = flat >> 3;           // pos 0..63
  const int bx = (xcd & 1) * 4 + (pos & 3);
  const int by = (xcd >> 1) * 16 + (pos >> 2);
  const int m0 = by * 64, n0 = bx * 128;

  const int wm = (wave >> 1) * 32, wn = (wave & 1) * 64;
  const int srow = lane >> 2;
  const int scol = (((lane & 3) ^ ((lane >> 3) & 3)) * 8);

  f32x4 acc[2][4] = {};

  const bf16* Ag = A    + (size_t)(m0 + wave * 16 + (lane >> 2)) * D_MODEL + scol;
  const bf16* Bg = g.BT + (size_t)(n0 + wave * 32 + srow) * D_MODEL + scol;
  const int lbaseA = wave * 16 * 32;
  const int lbaseB = wave * 32 * 32;
  const int rsw = (quad ^ ((l16 >> 1) & 3)) * 8;

  gload_lds16(Ag,                &As[0][lbaseA]);
  gload_lds16(Bg,                &Bs[0][lbaseB]);
  gload_lds16(Bg + 16 * D_MODEL, &Bs[0][lbaseB + 16 * 32]);
  __syncthreads();

  int cur = 0;
  for (int kt = 0; kt < D_MODEL; kt += 32, cur ^= 1) {
    if (kt + 32 < D_MODEL) {
      const int nxt = cur ^ 1;
      gload_lds16(Ag + kt + 32,                &As[nxt][lbaseA]);
      gload_lds16(Bg + kt + 32,                &Bs[nxt][lbaseB]);
      gload_lds16(Bg + kt + 32 + 16 * D_MODEL, &Bs[nxt][lbaseB + 16 * 32]);
    }

    bf16x8 af[2], bfv[4];
#pragma unroll
    for (int mi = 0; mi < 2; ++mi)
      af[mi] = *(const bf16x8*)(&As[cur][(wm + mi * 16 + l16) * 32 + rsw]);
#pragma unroll
    for (int ni = 0; ni < 4; ++ni)
      bfv[ni] = *(const bf16x8*)(&Bs[cur][(wn + ni * 16 + l16) * 32 + rsw]);
#pragma unroll
    for (int mi = 0; mi < 2; ++mi)
#pragma unroll
      for (int ni = 0; ni < 4; ++ni)
        acc[mi][ni] = __builtin_amdgcn_mfma_f32_16x16x32_bf16(
            af[mi], bfv[ni], acc[mi][ni], 0, 0, 0);

    __syncthreads();
  }

#pragma unroll
  for (int mi = 0; mi < 2; ++mi) {
    const int row0 = m0 + wm + mi * 16 + quad * 4;
#pragma unroll
    for (int ni = 0; ni < 4; ++ni) {
      const int col  = n0 + wn + ni * 16 + l16;
      const float bv = (float)g.bias[col];
      if (flag) {
        bf16* op = (bf16*)g.out + (size_t)row0 * D_MODEL + col;
#pragma unroll
        for (int r = 0; r < 4; ++r)
          op[(size_t)r * D_MODEL] = (bf16)(acc[mi][ni][r] + bv);
      } else {
        float* op = (float*)g.out + (size_t)row0 * D_MODEL + col;
#pragma unroll
        for (int r = 0; r < 4; ++r)
          op[(size_t)r * D_MODEL] = acc[mi][ni][r] + bv;
      }
    }
  }
}

// ---------------------------------------------------------------- attention
// grid (16 q-tiles, 32 bh) remapped R13: flat = y*16+x, xcd = flat&7,
// g = flat>>3, bh = xcd + (g>>4)*8, qt = g&15. Bijective; XCD k owns
// bh in {k,k+8,k+16,k+24} x all 16 q-tiles -> per-XCD concurrent K/V
// working set = 4 x 256KB = 1MB (L2-resident).
// 256 thr = 4 waves; wave w owns q-rows [q0+w*32, +32) as two 16-row
// sub-tiles. Compact keys, 64-key blocks. Static-max softmax; pad keys
// killed by -30000 penalty. K/V reg prefetch one block ahead; setprio
// around MFMA clusters (R12).
__global__ __launch_bounds__(256) void attn(
    const bf16* __restrict__ Qh, const bf16* __restrict__ Kc,
    const bf16* __restrict__ Vc, const int* __restrict__ nbp,
    bf16* __restrict__ Oh)
{
  const int flat = blockIdx.y * 16 + blockIdx.x;
  const int xcd = flat & 7, grp = flat >> 3;     // grp 0..63
  const int bh = xcd + (grp >> 4) * 8;           // 4 bh per XCD
  const int b  = bh >> 4;
  const int h  = bh & 15;
  const int q0 = (grp & 15) * 128;
  const int tid = threadIdx.x, wave = tid >> 6, lane = tid & 63;
  const int quad = lane >> 4, l16 = lane & 15;

  __shared__ __align__(16) bf16 Ks[64][72];
  __shared__ __align__(16) bf16 Vts[64][72];    // [d][j']
  __shared__ __align__(16) bf16 Ps[4][32][72];  // per-wave P tile

  const int nbv = nbp[b];
  const int nb_pad = (nbv + 63) & ~63;

  // Q fragments straight from global (Q is pre-scaled by QSCALE)
  const bf16* Qg = Qh + ((size_t)bh * S_LEN + q0 + wave * 32) * DEPTH;
  bf16x8 aq00 = *(const bf16x8*)(Qg + (size_t)l16 * DEPTH + quad * 8);
  bf16x8 aq01 = *(const bf16x8*)(Qg + (size_t)l16 * DEPTH + 32 + quad * 8);
  bf16x8 aq10 = *(const bf16x8*)(Qg + (size_t)(16 + l16) * DEPTH + quad * 8);
  bf16x8 aq11 = *(const bf16x8*)(Qg + (size_t)(16 + l16) * DEPTH + 32 + quad * 8);

  bf16x8 ones;
#pragma unroll
  for (int j = 0; j < 8; ++j) ones[j] = (bf16)1.0f;

  f32x4 o_acc[2][4] = {};
  f32x4 l_acc[2] = {};

  const bf16* Kg = Kc + (size_t)bh * S_LEN * DEPTH;
  const bf16* Vg = Vc + (size_t)bh * DEPTH * S_LEN;

  // staging coords: thread covers rows sr0 and sr1 (=sr0+32), 8 cols each
  const int sr0 = tid >> 3, sc0 = (tid & 7) * 8;
  const int sr1 = sr0 + 32;

  bf16x8 kr0, kr1, vr0, vr1;
  {
    kr0 = *(const bf16x8*)(Kg + (size_t)sr0 * DEPTH + sc0);
    kr1 = *(const bf16x8*)(Kg + (size_t)sr1 * DEPTH + sc0);
    vr0 = *(const bf16x8*)(Vg + (size_t)sr0 * S_LEN + sc0);
    vr1 = *(const bf16x8*)(Vg + (size_t)sr1 * S_LEN + sc0);
  }

  for (int kb = 0; kb < nb_pad; kb += 64) {
    __syncthreads();                       // previous tile fully consumed
    *(bf16x8*)(&Ks[sr0][sc0])  = kr0;
    *(bf16x8*)(&Ks[sr1][sc0])  = kr1;
    *(bf16x8*)(&Vts[sr0][sc0]) = vr0;
    *(bf16x8*)(&Vts[sr1][sc0]) = vr1;
    __syncthreads();                       // tile published
    if (kb + 64 < nb_pad) {                // prefetch next (overlaps compute)
      kr0 = *(const bf16x8*)(Kg + (size_t)(kb + 64 + sr0) * DEPTH + sc0);
      kr1 = *(const bf16x8*)(Kg + (size_t)(kb + 64 + sr1) * DEPTH + sc0);
      vr0 = *(const bf16x8*)(Vg + (size_t)sr0 * S_LEN + kb + 64 + sc0);
      vr1 = *(const bf16x8*)(Vg + (size_t)sr1 * S_LEN + kb + 64 + sc0);
    }

    // S = Q K^T : 32 q-rows x 64 keys; each bk pair feeds both q sub-tiles
    f32x4 sacc[2][4] = {};
    __builtin_amdgcn_s_setprio(1);
#pragma unroll
    for (int jn = 0; jn < 4; ++jn) {
      bf16x8 bk0 = *(const bf16x8*)(&Ks[jn * 16 + l16][quad * 8]);
      bf16x8 bk1 = *(const bf16x8*)(&Ks[jn * 16 + l16][32 + quad * 8]);
      sacc[0][jn] = __builtin_amdgcn_mfma_f32_16x16x32_bf16(aq00, bk0, sacc[0][jn], 0, 0, 0);
      sacc[0][jn] = __builtin_amdgcn_mfma_f32_16x16x32_bf16(aq01, bk1, sacc[0][jn], 0, 0, 0);
      sacc[1][jn] = __builtin_amdgcn_mfma_f32_16x16x32_bf16(aq10, bk0, sacc[1][jn], 0, 0, 0);
      sacc[1][jn] = __builtin_amdgcn_mfma_f32_16x16x32_bf16(aq11, bk1, sacc[1][jn], 0, 0, 0);
    }
    __builtin_amdgcn_s_setprio(0);

    // p = exp2(s - SMAX), pad keys -> exactly 0
#pragma unroll
    for (int jn = 0; jn < 4; ++jn) {
      const int key = kb + jn * 16 + l16;
      const float pen = (key < nbv) ? (-SMAX) : PADPEN;
#pragma unroll
      for (int qs = 0; qs < 2; ++qs)
#pragma unroll
        for (int r = 0; r < 4; ++r)
          Ps[wave][qs * 16 + quad * 4 + r][jn * 16 + l16] =
              (bf16)__builtin_amdgcn_exp2f(sacc[qs][jn][r] + pen);
    }

    // O += P @ V ; l += P @ 1  (Ps same-wave write->read: DS in-order)
    bf16x8 ap00 = *(const bf16x8*)(&Ps[wave][l16][quad * 8]);
    bf16x8 ap01 = *(const bf16x8*)(&Ps[wave][l16][32 + quad * 8]);
    bf16x8 ap10 = *(const bf16x8*)(&Ps[wave][16 + l16][quad * 8]);
    bf16x8 ap11 = *(const bf16x8*)(&Ps[wave][16 + l16][32 + quad * 8]);
    __builtin_amdgcn_s_setprio(1);
#pragma unroll
    for (int jd = 0; jd < 4; ++jd) {
      bf16x8 bv0 = *(const bf16x8*)(&Vts[jd * 16 + l16][quad * 8]);
      bf16x8 bv1 = *(const bf16x8*)(&Vts[jd * 16 + l16][32 + quad * 8]);
      o_acc[0][jd] = __builtin_amdgcn_mfma_f32_16x16x32_bf16(ap00, bv0, o_acc[0][jd], 0, 0, 0);
      o_acc[0][jd] = __builtin_amdgcn_mfma_f32_16x16x32_bf16(ap01, bv1, o_acc[0][jd], 0, 0, 0);
      o_acc[1][jd] = __builtin_amdgcn_mfma_f32_16x16x32_bf16(ap10, bv0, o_acc[1][jd], 0, 0, 0);
      o_acc[1][jd] = __builtin_amdgcn_mfma_f32_16x16x32_bf16(ap11, bv1, o_acc[1][jd], 0, 0, 0);
    }
    l_acc[0] = __builtin_amdgcn_mfma_f32_16x16x32_bf16(ap00, ones, l_acc[0], 0, 0, 0);
    l_acc[0] = __builtin_amdgcn_mfma_f32_16x16x32_bf16(ap01, ones, l_acc[0], 0, 0, 0);
    l_acc[1] = __builtin_amdgcn_mfma_f32_16x16x32_bf16(ap10, ones, l_acc[1], 0, 0, 0);
    l_acc[1] = __builtin_amdgcn_mfma_f32_16x16x32_bf16(ap11, ones, l_acc[1], 0, 0, 0);
    __builtin_amdgcn_s_setprio(0);
  }

#pragma unroll
  for (int qs = 0; qs < 2; ++qs) {
#pragma unroll
    for (int r = 0; r < 4; ++r) {
      const int s = q0 + wave * 32 + qs * 16 + quad * 4 + r;
      const float inv = 1.f / l_acc[qs][r];
#pragma unroll
      for (int jd = 0; jd < 4; ++jd) {
        const int d = jd * 16 + l16;
        Oh[(size_t)(b * S_LEN + s) * D_MODEL + h * DEPTH + d] =
            (bf16)(o_acc[qs][jd][r] * inv);
      }
    }
  }
}

// ---------------------------------------------------------------- launch
extern "C" void kernel_launch(void* const* d_in, const int* in_sizes, int n_in,
                              void* d_out, int out_size, void* d_ws, size_t ws_size,
                              hipStream_t stream)
{
  const void* q    = d_in[0];
  const void* k    = d_in[1];
  const void* v    = d_in[2];
  const int*  mask = (const int*)d_in[3];
  const void* wq   = d_in[4];
  const void* bq   = d_in[5];
  const void* wk   = d_in[6];
  const void* bk   = d_in[7];
  const void* wv   = d_in[8];
  const void* bv   = d_in[9];
  const void* wo   = d_in[10];
  const void* bo   = d_in[11];

  char* ws = (char*)d_ws;
  const size_t MB = 1u << 20;
  bf16* Qh  = (bf16*)(ws + 0 * MB);    // [b,h,s,d]   8 MB (pre-scaled)
  bf16* Kc  = (bf16*)(ws + 8 * MB);    // [b,h,j,d]   8 MB compact
  bf16* Vc  = (bf16*)(ws + 16 * MB);   // [b,h,d,j]   8 MB compact
  bf16* Oh  = (bf16*)(ws + 24 * MB);   // [b,s,(h d)] 8 MB
  bf16* wqT = (bf16*)(ws + 32 * MB);
  bf16* wkT = (bf16*)(ws + 34 * MB);
  bf16* wvT = (bf16*)(ws + 36 * MB);
  bf16* woT = (bf16*)(ws + 38 * MB);
  bf16* bqb = (bf16*)(ws + 40 * MB);
  bf16* bkb = (bf16*)(ws + 40 * MB + 4096);
  bf16* bvb = (bf16*)(ws + 40 * MB + 8192);
  bf16* bob = (bf16*)(ws + 40 * MB + 12288);
  int*  flag = (int*)(ws + 40 * MB + 32768);
  int*  cpos = (int*)(ws + 40 * MB + 65536);           // 16 KB
  int*  nb   = (int*)(ws + 40 * MB + 65536 + 16384);   // 8 B
  bf16* qb  = (bf16*)(ws + 41 * MB);   // f32-conversion buffers (flag==0 only)
  bf16* kb_ = (bf16*)(ws + 49 * MB);
  bf16* vb_ = (bf16*)(ws + 57 * MB);

  setup<<<7174, 256, 0, stream>>>(
      q, k, v, mask, wq, wk, wv, wo, bq, bk, bv, bo,
      wqT, wkT, wvT, woT, bqb, bkb, bvb, bob,
      qb, kb_, vb_, cpos, nb, flag);

  GArgs gq{qb,  q,  wqT, bqb, Qh, nullptr, 1};
  GArgs gk{kb_, k,  wkT, bkb, Kc, cpos,    3};
  GArgs gv{vb_, v,  wvT, bvb, Vc, cpos,    2};
  gemm_qkv<<<dim3(8, 32, 3), 256, 0, stream>>>(gq, gk, gv, flag);

  attn<<<dim3(16, 32), 256, 0, stream>>>(Qh, Kc, Vc, nb, Oh);

  GArgs go{Oh, Oh, woT, bob, d_out, nullptr, 0};
  gemm_out<<<dim3(8, 64), 256, 0, stream>>>(go, flag);
}